// Round 7
// baseline (556.904 us; speedup 1.0000x reference)
//
#include <hip/hip_runtime.h>

#define N_NODES 100000
#define N_EDGES 1600000
#define IN_DIM 128
#define HIDDEN 256
#define EMBED 64
#define K_STEPS 10

// binning geometry
#define NPB_SHIFT 11
#define NPB 2048                    // nodes per bucket
#define NBUCK 49                    // ceil(100000/2048)
#define TILE 4096                   // edges per bin tile
#define NTILES 391                  // ceil(1.6M/4096)
#define CAP 192                     // slots per (tile,bucket); mean 84, 12 sigma margin

typedef unsigned int u32;
typedef unsigned short u16;
using bf16x8 = __attribute__((ext_vector_type(8))) short;
using f32x4  = __attribute__((ext_vector_type(4))) float;

__device__ __forceinline__ float bflo(u32 u) { return __uint_as_float(u << 16); }
__device__ __forceinline__ float bfhi(u32 u) { return __uint_as_float(u & 0xffff0000u); }
__device__ __forceinline__ u16 f2bf(float f) {   // round-to-nearest-even
    u32 u = __float_as_uint(f);
    u += 0x7fffu + ((u >> 16) & 1u);
    return (u16)(u >> 16);
}

// ---------------- weight prep: transpose + bf16 convert ----------------
__global__ void conv_weights(const float* __restrict__ W1, const float* __restrict__ W2,
                             u16* __restrict__ W1T, u16* __restrict__ W2T)
{
    int i = blockIdx.x * 256 + threadIdx.x;
    if (i < IN_DIM * HIDDEN) {
        int n = i / IN_DIM, k = i % IN_DIM;
        W1T[i] = f2bf(W1[k * HIDDEN + n]);
    }
    int j = i - IN_DIM * HIDDEN;
    if (j >= 0 && j < HIDDEN * EMBED) {
        int n = j / HIDDEN, k = j % HIDDEN;
        W2T[j] = f2bf(W2[k * EMBED + n]);
    }
}

// ---------------- fused MLP via bf16 MFMA (no X staging, single barrier) ----------------
__device__ __forceinline__ bf16x8 ldx8(const float* __restrict__ p) {
    float4 a = *(const float4*)p;
    float4 b = *(const float4*)(p + 4);
    bf16x8 r;
    r[0] = (short)f2bf(a.x); r[1] = (short)f2bf(a.y);
    r[2] = (short)f2bf(a.z); r[3] = (short)f2bf(a.w);
    r[4] = (short)f2bf(b.x); r[5] = (short)f2bf(b.y);
    r[6] = (short)f2bf(b.z); r[7] = (short)f2bf(b.w);
    return r;
}

__global__ __launch_bounds__(256) void mlp_mfma(
    const float* __restrict__ x, const u16* __restrict__ W1T,
    const float* __restrict__ b1, const u16* __restrict__ W2T,
    const float* __restrict__ b2, const float* __restrict__ dinv,
    u16* __restrict__ x0bf, u16* __restrict__ g0bf, int n)
{
    __shared__ u16 H1s[64][264];   // 33.8 KB -> 4 blocks/CU
    int t = threadIdx.x;
    int rowBase = blockIdx.x * 64;
    int lane = t & 63, w = t >> 6;
    int lr = lane & 15, kg = lane >> 4;

    { // phase 1: H1 = relu(X@W1+b1); wave w owns cols w*64..+63; A direct from global
        int n0 = w * 64;
        f32x4 acc[4][4];
        #pragma unroll
        for (int m = 0; m < 4; ++m)
            #pragma unroll
            for (int nn = 0; nn < 4; ++nn) acc[m][nn] = (f32x4){0.f, 0.f, 0.f, 0.f};
        #pragma unroll
        for (int k0 = 0; k0 < IN_DIM; k0 += 32) {
            bf16x8 a[4], b[4];
            #pragma unroll
            for (int m = 0; m < 4; ++m) {
                int row = rowBase + m * 16 + lr;
                a[m] = (row < n) ? ldx8(x + (size_t)row * IN_DIM + k0 + kg * 8)
                                 : (bf16x8){0,0,0,0,0,0,0,0};
            }
            #pragma unroll
            for (int nn = 0; nn < 4; ++nn)
                b[nn] = *(const bf16x8*)(W1T + (size_t)(n0 + nn * 16 + lr) * IN_DIM + k0 + kg * 8);
            #pragma unroll
            for (int m = 0; m < 4; ++m)
                #pragma unroll
                for (int nn = 0; nn < 4; ++nn)
                    acc[m][nn] = __builtin_amdgcn_mfma_f32_16x16x32_bf16(a[m], b[nn], acc[m][nn], 0, 0, 0);
        }
        #pragma unroll
        for (int nn = 0; nn < 4; ++nn) {
            float bb = b1[n0 + nn * 16 + lr];
            #pragma unroll
            for (int m = 0; m < 4; ++m)
                #pragma unroll
                for (int r = 0; r < 4; ++r)
                    H1s[m * 16 + kg * 4 + r][n0 + nn * 16 + lr] = f2bf(fmaxf(acc[m][nn][r] + bb, 0.f));
        }
    }
    __syncthreads();

    { // phase 2: H0 = H1@W2+b2
        int r0 = w * 16;
        f32x4 acc[4];
        #pragma unroll
        for (int nn = 0; nn < 4; ++nn) acc[nn] = (f32x4){0.f, 0.f, 0.f, 0.f};
        #pragma unroll
        for (int k0 = 0; k0 < HIDDEN; k0 += 32) {
            bf16x8 a = *(const bf16x8*)&H1s[r0 + lr][k0 + kg * 8];
            #pragma unroll
            for (int nn = 0; nn < 4; ++nn) {
                bf16x8 b = *(const bf16x8*)(W2T + (size_t)(nn * 16 + lr) * HIDDEN + k0 + kg * 8);
                acc[nn] = __builtin_amdgcn_mfma_f32_16x16x32_bf16(a, b, acc[nn], 0, 0, 0);
            }
        }
        #pragma unroll
        for (int nn = 0; nn < 4; ++nn) {
            float bb = b2[nn * 16 + lr];
            #pragma unroll
            for (int r = 0; r < 4; ++r) {
                int rw = rowBase + r0 + kg * 4 + r;
                if (rw < n) {
                    float val = acc[nn][r] + bb;
                    size_t idx = (size_t)rw * EMBED + nn * 16 + lr;
                    x0bf[idx] = f2bf(val);
                    g0bf[idx] = f2bf(dinv[rw] * val);
                }
            }
        }
    }
}

// ---------------- graph prep ----------------
__global__ void zero_int(int* p, int n) {
    int i = blockIdx.x * 256 + threadIdx.x; if (i < n) p[i] = 0;
}
__global__ void calc_dinv(const int* __restrict__ cnt, float* __restrict__ dinv, int n) {
    int i = blockIdx.x * 256 + threadIdx.x;
    if (i < n) dinv[i] = rsqrtf((float)(cnt[i] + 1));
}
__global__ void block_reduce(const int* __restrict__ cnt, int* __restrict__ bsum, int n) {
    __shared__ int sh[256];
    int i = blockIdx.x * 256 + threadIdx.x;
    sh[threadIdx.x] = (i < n) ? cnt[i] : 0; __syncthreads();
    for (int o = 128; o > 0; o >>= 1) {
        if (threadIdx.x < o) sh[threadIdx.x] += sh[threadIdx.x + o];
        __syncthreads();
    }
    if (threadIdx.x == 0) bsum[blockIdx.x] = sh[0];
}
__global__ void scan_blk(int* bsum, int nb) {   // exclusive scan, nb <= 512
    __shared__ int sh[512];
    int t = threadIdx.x;
    int v = (t < nb) ? bsum[t] : 0;
    sh[t] = v; __syncthreads();
    for (int o = 1; o < 512; o <<= 1) {
        int a = (t >= o) ? sh[t - o] : 0;
        __syncthreads();
        sh[t] += a;
        __syncthreads();
    }
    if (t < nb) bsum[t] = sh[t] - v;
}
__global__ void block_scan(const int* __restrict__ cnt, const int* __restrict__ bsum,
                           int* __restrict__ off, int n) {
    __shared__ int sh[256];
    int t = threadIdx.x, i = blockIdx.x * 256 + t;
    int v = (i < n) ? cnt[i] : 0;
    sh[t] = v; __syncthreads();
    for (int o = 1; o < 256; o <<= 1) {
        int a = (t >= o) ? sh[t - o] : 0;
        __syncthreads();
        sh[t] += a;
        __syncthreads();
    }
    if (i < n) off[i] = bsum[blockIdx.x] + sh[t] - v;
}
__global__ void set_tail(int* off) { off[N_NODES] = N_EDGES; }

// ---- pass B: bin edges by dst bucket into tile-private slots + fused degree count ----
__global__ __launch_bounds__(256) void bin_edges(
    const int* __restrict__ row, const int* __restrict__ col,
    u32* __restrict__ slot, int* __restrict__ slotcnt,
    int* __restrict__ cnt, int e)
{
    __shared__ int bcur[NBUCK];
    int t = threadIdx.x;
    if (t < NBUCK) bcur[t] = 0;
    __syncthreads();
    int base = blockIdx.x * TILE;
    for (int i = t; i < TILE; i += 256) {
        int gi = base + i;
        if (gi >= e) break;
        int c = col[gi], r = row[gi];
        atomicAdd(&cnt[c], 1);                      // fused count_deg
        int b = c >> NPB_SHIFT;
        int pos = atomicAdd(&bcur[b], 1);
        if (pos < CAP)
            slot[((size_t)blockIdx.x * NBUCK + b) * CAP + pos] =
                (u32)r | ((u32)(c & (NPB - 1)) << 17);
    }
    __syncthreads();
    if (t < NBUCK) slotcnt[blockIdx.x * NBUCK + t] = min(bcur[t], CAP);
}

// ---- pass C: drain one bucket's slots into exact CSC; 1024 thr = 16 tile-drain waves ----
__global__ __launch_bounds__(1024) void csc_from_bins(
    const u32* __restrict__ slot, const int* __restrict__ slotcnt,
    const int* __restrict__ off, int* __restrict__ ew)
{
    __shared__ int cur[NPB];
    int b = blockIdx.x;
    int t = threadIdx.x;
    int vbase = b << NPB_SHIFT;
    int nv = min(NPB, N_NODES - vbase);
    for (int i = t; i < nv; i += 1024) cur[i] = off[vbase + i];
    __syncthreads();
    int wid = t >> 6, lane = t & 63;
    for (int tile = wid; tile < NTILES; tile += 16) {
        int n_tb = slotcnt[tile * NBUCK + b];
        const u32* seg = slot + ((size_t)tile * NBUCK + b) * CAP;
        for (int i = lane; i < n_tb; i += 64) {
            u32 u = seg[i];
            int p = atomicAdd(&cur[u >> 17], 1);
            ew[p] = (int)(u & 0x1FFFFu);
        }
    }
}

// ---------------- propagation: pull, 8 lanes/node x 16B/lane, unroll x8 ----------------
__global__ __launch_bounds__(256) void prop8(
    const int* __restrict__ off, const int* __restrict__ ew,
    const u32* __restrict__ gin, const u32* __restrict__ x0,
    const float* __restrict__ dinv,
    u32* __restrict__ gout, float* __restrict__ hout, int final_step)
{
    int t = threadIdx.x;
    int v = blockIdx.x * 32 + (t >> 3);
    int l = t & 7;
    const u32* base = gin + l * 4;
    int s = off[v], e = off[v + 1];

    float aL0 = 0.f, aH0 = 0.f, aL1 = 0.f, aH1 = 0.f;
    float aL2 = 0.f, aH2 = 0.f, aL3 = 0.f, aH3 = 0.f;

    int i = s;
    int pre = (4 - (s & 3)) & 3;
    if (pre > e - s) pre = e - s;
    for (int k = 0; k < pre; ++k, ++i) {
        uint4 r = *(const uint4*)(base + (size_t)ew[i] * 32);
        aL0 += bflo(r.x); aH0 += bfhi(r.x);
        aL1 += bflo(r.y); aH1 += bfhi(r.y);
        aL2 += bflo(r.z); aH2 += bfhi(r.z);
        aL3 += bflo(r.w); aH3 += bfhi(r.w);
    }
    for (; i + 8 <= e; i += 8) {
        int4 eA = *(const int4*)(ew + i);
        int4 eB = *(const int4*)(ew + i + 4);
        uint4 r0 = *(const uint4*)(base + (size_t)eA.x * 32);
        uint4 r1 = *(const uint4*)(base + (size_t)eA.y * 32);
        uint4 r2 = *(const uint4*)(base + (size_t)eA.z * 32);
        uint4 r3 = *(const uint4*)(base + (size_t)eA.w * 32);
        uint4 r4 = *(const uint4*)(base + (size_t)eB.x * 32);
        uint4 r5 = *(const uint4*)(base + (size_t)eB.y * 32);
        uint4 r6 = *(const uint4*)(base + (size_t)eB.z * 32);
        uint4 r7 = *(const uint4*)(base + (size_t)eB.w * 32);
        aL0 += (bflo(r0.x) + bflo(r1.x)) + (bflo(r2.x) + bflo(r3.x))
             + (bflo(r4.x) + bflo(r5.x)) + (bflo(r6.x) + bflo(r7.x));
        aH0 += (bfhi(r0.x) + bfhi(r1.x)) + (bfhi(r2.x) + bfhi(r3.x))
             + (bfhi(r4.x) + bfhi(r5.x)) + (bfhi(r6.x) + bfhi(r7.x));
        aL1 += (bflo(r0.y) + bflo(r1.y)) + (bflo(r2.y) + bflo(r3.y))
             + (bflo(r4.y) + bflo(r5.y)) + (bflo(r6.y) + bflo(r7.y));
        aH1 += (bfhi(r0.y) + bfhi(r1.y)) + (bfhi(r2.y) + bfhi(r3.y))
             + (bfhi(r4.y) + bfhi(r5.y)) + (bfhi(r6.y) + bfhi(r7.y));
        aL2 += (bflo(r0.z) + bflo(r1.z)) + (bflo(r2.z) + bflo(r3.z))
             + (bflo(r4.z) + bflo(r5.z)) + (bflo(r6.z) + bflo(r7.z));
        aH2 += (bfhi(r0.z) + bfhi(r1.z)) + (bfhi(r2.z) + bfhi(r3.z))
             + (bfhi(r4.z) + bfhi(r5.z)) + (bfhi(r6.z) + bfhi(r7.z));
        aL3 += (bflo(r0.w) + bflo(r1.w)) + (bflo(r2.w) + bflo(r3.w))
             + (bflo(r4.w) + bflo(r5.w)) + (bflo(r6.w) + bflo(r7.w));
        aH3 += (bfhi(r0.w) + bfhi(r1.w)) + (bfhi(r2.w) + bfhi(r3.w))
             + (bfhi(r4.w) + bfhi(r5.w)) + (bfhi(r6.w) + bfhi(r7.w));
    }
    for (; i + 4 <= e; i += 4) {
        int4 e4 = *(const int4*)(ew + i);
        uint4 r0 = *(const uint4*)(base + (size_t)e4.x * 32);
        uint4 r1 = *(const uint4*)(base + (size_t)e4.y * 32);
        uint4 r2 = *(const uint4*)(base + (size_t)e4.z * 32);
        uint4 r3 = *(const uint4*)(base + (size_t)e4.w * 32);
        aL0 += (bflo(r0.x) + bflo(r1.x)) + (bflo(r2.x) + bflo(r3.x));
        aH0 += (bfhi(r0.x) + bfhi(r1.x)) + (bfhi(r2.x) + bfhi(r3.x));
        aL1 += (bflo(r0.y) + bflo(r1.y)) + (bflo(r2.y) + bflo(r3.y));
        aH1 += (bfhi(r0.y) + bfhi(r1.y)) + (bfhi(r2.y) + bfhi(r3.y));
        aL2 += (bflo(r0.z) + bflo(r1.z)) + (bflo(r2.z) + bflo(r3.z));
        aH2 += (bfhi(r0.z) + bfhi(r1.z)) + (bfhi(r2.z) + bfhi(r3.z));
        aL3 += (bflo(r0.w) + bflo(r1.w)) + (bflo(r2.w) + bflo(r3.w));
        aH3 += (bfhi(r0.w) + bfhi(r1.w)) + (bfhi(r2.w) + bfhi(r3.w));
    }
    for (; i < e; ++i) {
        uint4 r = *(const uint4*)(base + (size_t)ew[i] * 32);
        aL0 += bflo(r.x); aH0 += bfhi(r.x);
        aL1 += bflo(r.y); aH1 += bfhi(r.y);
        aL2 += bflo(r.z); aH2 += bfhi(r.z);
        aL3 += bflo(r.w); aH3 += bfhi(r.w);
    }

    uint4 rs = *(const uint4*)(base + (size_t)v * 32);
    uint4 rx = *(const uint4*)(x0 + (size_t)v * 32 + l * 4);
    float dv = dinv[v];
    float h0 = 0.9f * dv * (aL0 + bflo(rs.x)) + 0.1f * bflo(rx.x);
    float h1 = 0.9f * dv * (aH0 + bfhi(rs.x)) + 0.1f * bfhi(rx.x);
    float h2 = 0.9f * dv * (aL1 + bflo(rs.y)) + 0.1f * bflo(rx.y);
    float h3 = 0.9f * dv * (aH1 + bfhi(rs.y)) + 0.1f * bfhi(rx.y);
    float h4 = 0.9f * dv * (aL2 + bflo(rs.z)) + 0.1f * bflo(rx.z);
    float h5 = 0.9f * dv * (aH2 + bfhi(rs.z)) + 0.1f * bfhi(rx.z);
    float h6 = 0.9f * dv * (aL3 + bflo(rs.w)) + 0.1f * bflo(rx.w);
    float h7 = 0.9f * dv * (aH3 + bfhi(rs.w)) + 0.1f * bfhi(rx.w);

    if (final_step) {
        float* o = hout + (size_t)v * EMBED + l * 8;
        *(float4*)(o)     = make_float4(h0, h1, h2, h3);
        *(float4*)(o + 4) = make_float4(h4, h5, h6, h7);
    } else {
        uint4 g;
        g.x = (u32)f2bf(dv * h0) | ((u32)f2bf(dv * h1) << 16);
        g.y = (u32)f2bf(dv * h2) | ((u32)f2bf(dv * h3) << 16);
        g.z = (u32)f2bf(dv * h4) | ((u32)f2bf(dv * h5) << 16);
        g.w = (u32)f2bf(dv * h6) | ((u32)f2bf(dv * h7) << 16);
        *(uint4*)(gout + (size_t)v * 32 + l * 4) = g;
    }
}

extern "C" void kernel_launch(void* const* d_in, const int* in_sizes, int n_in,
                              void* d_out, int out_size, void* d_ws, size_t ws_size,
                              hipStream_t stream)
{
    const float* x  = (const float*)d_in[0];
    const int*   ei = (const int*)d_in[1];
    const float* W1 = (const float*)d_in[2];
    const float* b1 = (const float*)d_in[3];
    const float* W2 = (const float*)d_in[4];
    const float* b2 = (const float*)d_in[5];
    float* out = (float*)d_out;
    const int* row = ei;
    const int* col = ei + N_EDGES;

    // permanent carve-out (~46 MB)
    char* w = (char*)d_ws;
    u16* x0bf = (u16*)w; w += (size_t)N_NODES * EMBED * 2;   // 12.8 MB
    u16* gA   = (u16*)w; w += (size_t)N_NODES * EMBED * 2;   // 12.8 MB
    u16* gB   = (u16*)w; w += (size_t)N_NODES * EMBED * 2;   // 12.8 MB
    int* ew   = (int*)w;  w += (size_t)N_EDGES * 4;          // 6.4 MB
    int* cnt  = (int*)w;  w += (size_t)N_NODES * 4;
    int* off  = (int*)w;  w += ((size_t)(N_NODES + 1) * 4 + 12) & ~15ull;
    int* bsum = (int*)w;  w += 4096;
    float* dinv = (float*)w; w += (size_t)N_NODES * 4;
    u16* W1T = (u16*)w; w += (size_t)IN_DIM * HIDDEN * 2;
    u16* W2T = (u16*)w; w += (size_t)HIDDEN * EMBED * 2;

    // transient binning storage aliased onto x0bf+gA (dead until mlp_mfma runs)
    u32* slot    = (u32*)x0bf;                                       // 14.72 MB
    int* slotcnt = (int*)(x0bf + (size_t)NTILES * NBUCK * CAP * 2);  // after slots

    int nbN = (N_NODES + 255) / 256;

    conv_weights<<<(IN_DIM * HIDDEN + HIDDEN * EMBED + 255) / 256, 256, 0, stream>>>(W1, W2, W1T, W2T);
    zero_int<<<nbN, 256, 0, stream>>>(cnt, N_NODES);
    bin_edges<<<NTILES, 256, 0, stream>>>(row, col, slot, slotcnt, cnt, N_EDGES);
    calc_dinv<<<nbN, 256, 0, stream>>>(cnt, dinv, N_NODES);

    block_reduce<<<nbN, 256, 0, stream>>>(cnt, bsum, N_NODES);
    scan_blk<<<1, 512, 0, stream>>>(bsum, nbN);
    block_scan<<<nbN, 256, 0, stream>>>(cnt, bsum, off, N_NODES);
    set_tail<<<1, 1, 0, stream>>>(off);

    csc_from_bins<<<NBUCK, 1024, 0, stream>>>(slot, slotcnt, off, ew);

    // MLP after binning (slots alias x0bf/gA)
    mlp_mfma<<<(N_NODES + 63) / 64, 256, 0, stream>>>(x, W1T, b1, W2T, b2, dinv, x0bf, gA, N_NODES);

    // K=10 steps
    const u32* gin = (const u32*)gA;
    for (int s = 0; s < K_STEPS; ++s) {
        int fin = (s == K_STEPS - 1);
        u32* gout = (u32*)((s & 1) ? gA : gB);
        prop8<<<N_NODES / 32, 256, 0, stream>>>(off, ew, gin, (const u32*)x0bf, dinv,
                                                gout, out, fin);
        gin = gout;
    }
}

// Round 8
// 517.121 us; speedup vs baseline: 1.0769x; 1.0769x over previous
//
#include <hip/hip_runtime.h>

#define N_NODES 100000
#define N_EDGES 1600000
#define IN_DIM 128
#define HIDDEN 256
#define EMBED 64
#define K_STEPS 10

// binning geometry
#define NPB_SHIFT 11
#define NPB 2048                    // nodes per bucket
#define NBUCK 49                    // ceil(100000/2048)
#define TILE 4096                   // edges per bin tile
#define NTILES 391                  // ceil(1.6M/4096)
#define CAP 192                     // slots per (tile,bucket); mean 84, 12 sigma margin

typedef unsigned int u32;
typedef unsigned short u16;
using bf16x8 = __attribute__((ext_vector_type(8))) short;
using f32x4  = __attribute__((ext_vector_type(4))) float;

__device__ __forceinline__ float bflo(u32 u) { return __uint_as_float(u << 16); }
__device__ __forceinline__ float bfhi(u32 u) { return __uint_as_float(u & 0xffff0000u); }
__device__ __forceinline__ u16 f2bf(float f) {   // round-to-nearest-even
    u32 u = __float_as_uint(f);
    u += 0x7fffu + ((u >> 16) & 1u);
    return (u16)(u >> 16);
}

// ---------------- weight prep: transpose + bf16 convert ----------------
__global__ void conv_weights(const float* __restrict__ W1, const float* __restrict__ W2,
                             u16* __restrict__ W1T, u16* __restrict__ W2T)
{
    int i = blockIdx.x * 256 + threadIdx.x;
    if (i < IN_DIM * HIDDEN) {
        int n = i / IN_DIM, k = i % IN_DIM;
        W1T[i] = f2bf(W1[k * HIDDEN + n]);
    }
    int j = i - IN_DIM * HIDDEN;
    if (j >= 0 && j < HIDDEN * EMBED) {
        int n = j / HIDDEN, k = j % HIDDEN;
        W2T[j] = f2bf(W2[k * EMBED + n]);
    }
}

// ---------------- fused MLP via bf16 MFMA; 32-row tile, 25.6 KB LDS -> 6 blocks/CU ----------------
__global__ __launch_bounds__(256, 6) void mlp_mfma(
    const float* __restrict__ x, const u16* __restrict__ W1T,
    const float* __restrict__ b1, const u16* __restrict__ W2T,
    const float* __restrict__ b2, const float* __restrict__ dinv,
    u16* __restrict__ x0bf, u16* __restrict__ g0bf, int n)
{
    __shared__ u16 Xs[32][136];    // 8.7 KB
    __shared__ u16 H1s[32][264];   // 16.9 KB
    int t = threadIdx.x;
    int rowBase = blockIdx.x * 32;
    int lane = t & 63, w = t >> 6;
    int lr = lane & 15, kg = lane >> 4;

    // stage X tile (32 x 128 fp32 -> bf16 LDS), coalesced float4
    for (int i = t; i < 32 * 32; i += 256) {
        int row = i >> 5, c4 = (i & 31) * 4;
        float4 v = make_float4(0.f, 0.f, 0.f, 0.f);
        if (rowBase + row < n) v = *(const float4*)(x + (size_t)(rowBase + row) * IN_DIM + c4);
        Xs[row][c4 + 0] = f2bf(v.x); Xs[row][c4 + 1] = f2bf(v.y);
        Xs[row][c4 + 2] = f2bf(v.z); Xs[row][c4 + 3] = f2bf(v.w);
    }
    __syncthreads();

    { // phase 1: H1[32][256] = relu(X@W1+b1); wave w owns cols w*64..+63
        int n0 = w * 64;
        f32x4 acc[2][4];
        #pragma unroll
        for (int m = 0; m < 2; ++m)
            #pragma unroll
            for (int nn = 0; nn < 4; ++nn) acc[m][nn] = (f32x4){0.f, 0.f, 0.f, 0.f};
        #pragma unroll
        for (int k0 = 0; k0 < IN_DIM; k0 += 32) {
            bf16x8 a[2], b[4];
            #pragma unroll
            for (int m = 0; m < 2; ++m) a[m] = *(const bf16x8*)&Xs[m * 16 + lr][k0 + kg * 8];
            #pragma unroll
            for (int nn = 0; nn < 4; ++nn)
                b[nn] = *(const bf16x8*)(W1T + (size_t)(n0 + nn * 16 + lr) * IN_DIM + k0 + kg * 8);
            #pragma unroll
            for (int m = 0; m < 2; ++m)
                #pragma unroll
                for (int nn = 0; nn < 4; ++nn)
                    acc[m][nn] = __builtin_amdgcn_mfma_f32_16x16x32_bf16(a[m], b[nn], acc[m][nn], 0, 0, 0);
        }
        #pragma unroll
        for (int nn = 0; nn < 4; ++nn) {
            float bb = b1[n0 + nn * 16 + lr];
            #pragma unroll
            for (int m = 0; m < 2; ++m)
                #pragma unroll
                for (int r = 0; r < 4; ++r)
                    H1s[m * 16 + kg * 4 + r][n0 + nn * 16 + lr] = f2bf(fmaxf(acc[m][nn][r] + bb, 0.f));
        }
    }
    __syncthreads();

    { // phase 2: H0[32][64] = H1@W2+b2; wave w: rows (w&1)*16, cols (w>>1)*32
        int r0 = (w & 1) * 16, c0 = (w >> 1) * 32;
        f32x4 acc[2];
        #pragma unroll
        for (int nn = 0; nn < 2; ++nn) acc[nn] = (f32x4){0.f, 0.f, 0.f, 0.f};
        #pragma unroll
        for (int k0 = 0; k0 < HIDDEN; k0 += 32) {
            bf16x8 a = *(const bf16x8*)&H1s[r0 + lr][k0 + kg * 8];
            #pragma unroll
            for (int nn = 0; nn < 2; ++nn) {
                bf16x8 b = *(const bf16x8*)(W2T + (size_t)(c0 + nn * 16 + lr) * HIDDEN + k0 + kg * 8);
                acc[nn] = __builtin_amdgcn_mfma_f32_16x16x32_bf16(a, b, acc[nn], 0, 0, 0);
            }
        }
        #pragma unroll
        for (int nn = 0; nn < 2; ++nn) {
            float bb = b2[c0 + nn * 16 + lr];
            #pragma unroll
            for (int r = 0; r < 4; ++r) {
                int rw = rowBase + r0 + kg * 4 + r;
                if (rw < n) {
                    float val = acc[nn][r] + bb;
                    size_t idx = (size_t)rw * EMBED + c0 + nn * 16 + lr;
                    x0bf[idx] = f2bf(val);
                    g0bf[idx] = f2bf(dinv[rw] * val);
                }
            }
        }
    }
}

// ---------------- graph prep ----------------
__global__ void zero_int(int* p, int n) {
    int i = blockIdx.x * 256 + threadIdx.x; if (i < n) p[i] = 0;
}
__global__ void calc_dinv(const int* __restrict__ cnt, float* __restrict__ dinv, int n) {
    int i = blockIdx.x * 256 + threadIdx.x;
    if (i < n) dinv[i] = rsqrtf((float)(cnt[i] + 1));
}
__global__ void block_reduce(const int* __restrict__ cnt, int* __restrict__ bsum, int n) {
    __shared__ int sh[256];
    int i = blockIdx.x * 256 + threadIdx.x;
    sh[threadIdx.x] = (i < n) ? cnt[i] : 0; __syncthreads();
    for (int o = 128; o > 0; o >>= 1) {
        if (threadIdx.x < o) sh[threadIdx.x] += sh[threadIdx.x + o];
        __syncthreads();
    }
    if (threadIdx.x == 0) bsum[blockIdx.x] = sh[0];
}
__global__ void scan_blk(int* bsum, int nb) {   // exclusive scan, nb <= 512
    __shared__ int sh[512];
    int t = threadIdx.x;
    int v = (t < nb) ? bsum[t] : 0;
    sh[t] = v; __syncthreads();
    for (int o = 1; o < 512; o <<= 1) {
        int a = (t >= o) ? sh[t - o] : 0;
        __syncthreads();
        sh[t] += a;
        __syncthreads();
    }
    if (t < nb) bsum[t] = sh[t] - v;
}
__global__ void block_scan(const int* __restrict__ cnt, const int* __restrict__ bsum,
                           int* __restrict__ off, int n) {
    __shared__ int sh[256];
    int t = threadIdx.x, i = blockIdx.x * 256 + t;
    int v = (i < n) ? cnt[i] : 0;
    sh[t] = v; __syncthreads();
    for (int o = 1; o < 256; o <<= 1) {
        int a = (t >= o) ? sh[t - o] : 0;
        __syncthreads();
        sh[t] += a;
        __syncthreads();
    }
    if (i < n) off[i] = bsum[blockIdx.x] + sh[t] - v;
}
__global__ void set_tail(int* off) { off[N_NODES] = N_EDGES; }

// ---- pass B: bin edges by dst bucket into tile-private slots + fused degree count ----
__global__ __launch_bounds__(256) void bin_edges(
    const int* __restrict__ row, const int* __restrict__ col,
    u32* __restrict__ slot, int* __restrict__ slotcnt,
    int* __restrict__ cnt, int e)
{
    __shared__ int bcur[NBUCK];
    int t = threadIdx.x;
    if (t < NBUCK) bcur[t] = 0;
    __syncthreads();
    int base = blockIdx.x * TILE;
    for (int i = t; i < TILE; i += 256) {
        int gi = base + i;
        if (gi >= e) break;
        int c = col[gi], r = row[gi];
        atomicAdd(&cnt[c], 1);                      // fused count_deg
        int b = c >> NPB_SHIFT;
        int pos = atomicAdd(&bcur[b], 1);
        if (pos < CAP)
            slot[((size_t)blockIdx.x * NBUCK + b) * CAP + pos] =
                (u32)r | ((u32)(c & (NPB - 1)) << 17);
    }
    __syncthreads();
    if (t < NBUCK) slotcnt[blockIdx.x * NBUCK + t] = min(bcur[t], CAP);
}

// ---- pass C: drain one bucket's slots into exact CSC; 1024 thr = 16 tile-drain waves ----
__global__ __launch_bounds__(1024) void csc_from_bins(
    const u32* __restrict__ slot, const int* __restrict__ slotcnt,
    const int* __restrict__ off, int* __restrict__ ew)
{
    __shared__ int cur[NPB];
    int b = blockIdx.x;
    int t = threadIdx.x;
    int vbase = b << NPB_SHIFT;
    int nv = min(NPB, N_NODES - vbase);
    for (int i = t; i < nv; i += 1024) cur[i] = off[vbase + i];
    __syncthreads();
    int wid = t >> 6, lane = t & 63;
    for (int tile = wid; tile < NTILES; tile += 16) {
        int n_tb = slotcnt[tile * NBUCK + b];
        const u32* seg = slot + ((size_t)tile * NBUCK + b) * CAP;
        for (int i = lane; i < n_tb; i += 64) {
            u32 u = seg[i];
            int p = atomicAdd(&cur[u >> 17], 1);
            ew[p] = (int)(u & 0x1FFFFu);
        }
    }
}

// ---------------- propagation: pull, 8 lanes/node x 16B/lane, unroll x4 (proven) ----------------
__global__ __launch_bounds__(256) void prop8(
    const int* __restrict__ off, const int* __restrict__ ew,
    const u32* __restrict__ gin, const u32* __restrict__ x0,
    const float* __restrict__ dinv,
    u32* __restrict__ gout, float* __restrict__ hout, int final_step)
{
    int t = threadIdx.x;
    int v = blockIdx.x * 32 + (t >> 3);
    int l = t & 7;
    const u32* base = gin + l * 4;
    int s = off[v], e = off[v + 1];

    float aL0 = 0.f, aH0 = 0.f, aL1 = 0.f, aH1 = 0.f;
    float aL2 = 0.f, aH2 = 0.f, aL3 = 0.f, aH3 = 0.f;

    int i = s;
    int pre = (4 - (s & 3)) & 3;
    if (pre > e - s) pre = e - s;
    for (int k = 0; k < pre; ++k, ++i) {
        uint4 r = *(const uint4*)(base + (size_t)ew[i] * 32);
        aL0 += bflo(r.x); aH0 += bfhi(r.x);
        aL1 += bflo(r.y); aH1 += bfhi(r.y);
        aL2 += bflo(r.z); aH2 += bfhi(r.z);
        aL3 += bflo(r.w); aH3 += bfhi(r.w);
    }
    for (; i + 4 <= e; i += 4) {
        int4 e4 = *(const int4*)(ew + i);
        uint4 r0 = *(const uint4*)(base + (size_t)e4.x * 32);
        uint4 r1 = *(const uint4*)(base + (size_t)e4.y * 32);
        uint4 r2 = *(const uint4*)(base + (size_t)e4.z * 32);
        uint4 r3 = *(const uint4*)(base + (size_t)e4.w * 32);
        aL0 += (bflo(r0.x) + bflo(r1.x)) + (bflo(r2.x) + bflo(r3.x));
        aH0 += (bfhi(r0.x) + bfhi(r1.x)) + (bfhi(r2.x) + bfhi(r3.x));
        aL1 += (bflo(r0.y) + bflo(r1.y)) + (bflo(r2.y) + bflo(r3.y));
        aH1 += (bfhi(r0.y) + bfhi(r1.y)) + (bfhi(r2.y) + bfhi(r3.y));
        aL2 += (bflo(r0.z) + bflo(r1.z)) + (bflo(r2.z) + bflo(r3.z));
        aH2 += (bfhi(r0.z) + bfhi(r1.z)) + (bfhi(r2.z) + bfhi(r3.z));
        aL3 += (bflo(r0.w) + bflo(r1.w)) + (bflo(r2.w) + bflo(r3.w));
        aH3 += (bfhi(r0.w) + bfhi(r1.w)) + (bfhi(r2.w) + bfhi(r3.w));
    }
    for (; i < e; ++i) {
        uint4 r = *(const uint4*)(base + (size_t)ew[i] * 32);
        aL0 += bflo(r.x); aH0 += bfhi(r.x);
        aL1 += bflo(r.y); aH1 += bfhi(r.y);
        aL2 += bflo(r.z); aH2 += bfhi(r.z);
        aL3 += bflo(r.w); aH3 += bfhi(r.w);
    }

    uint4 rs = *(const uint4*)(base + (size_t)v * 32);
    uint4 rx = *(const uint4*)(x0 + (size_t)v * 32 + l * 4);
    float dv = dinv[v];
    float h0 = 0.9f * dv * (aL0 + bflo(rs.x)) + 0.1f * bflo(rx.x);
    float h1 = 0.9f * dv * (aH0 + bfhi(rs.x)) + 0.1f * bfhi(rx.x);
    float h2 = 0.9f * dv * (aL1 + bflo(rs.y)) + 0.1f * bflo(rx.y);
    float h3 = 0.9f * dv * (aH1 + bfhi(rs.y)) + 0.1f * bfhi(rx.y);
    float h4 = 0.9f * dv * (aL2 + bflo(rs.z)) + 0.1f * bflo(rx.z);
    float h5 = 0.9f * dv * (aH2 + bfhi(rs.z)) + 0.1f * bfhi(rx.z);
    float h6 = 0.9f * dv * (aL3 + bflo(rs.w)) + 0.1f * bflo(rx.w);
    float h7 = 0.9f * dv * (aH3 + bfhi(rs.w)) + 0.1f * bfhi(rx.w);

    if (final_step) {
        float* o = hout + (size_t)v * EMBED + l * 8;
        *(float4*)(o)     = make_float4(h0, h1, h2, h3);
        *(float4*)(o + 4) = make_float4(h4, h5, h6, h7);
    } else {
        uint4 g;
        g.x = (u32)f2bf(dv * h0) | ((u32)f2bf(dv * h1) << 16);
        g.y = (u32)f2bf(dv * h2) | ((u32)f2bf(dv * h3) << 16);
        g.z = (u32)f2bf(dv * h4) | ((u32)f2bf(dv * h5) << 16);
        g.w = (u32)f2bf(dv * h6) | ((u32)f2bf(dv * h7) << 16);
        *(uint4*)(gout + (size_t)v * 32 + l * 4) = g;
    }
}

extern "C" void kernel_launch(void* const* d_in, const int* in_sizes, int n_in,
                              void* d_out, int out_size, void* d_ws, size_t ws_size,
                              hipStream_t stream)
{
    const float* x  = (const float*)d_in[0];
    const int*   ei = (const int*)d_in[1];
    const float* W1 = (const float*)d_in[2];
    const float* b1 = (const float*)d_in[3];
    const float* W2 = (const float*)d_in[4];
    const float* b2 = (const float*)d_in[5];
    float* out = (float*)d_out;
    const int* row = ei;
    const int* col = ei + N_EDGES;

    // permanent carve-out (~46 MB)
    char* w = (char*)d_ws;
    u16* x0bf = (u16*)w; w += (size_t)N_NODES * EMBED * 2;   // 12.8 MB
    u16* gA   = (u16*)w; w += (size_t)N_NODES * EMBED * 2;   // 12.8 MB
    u16* gB   = (u16*)w; w += (size_t)N_NODES * EMBED * 2;   // 12.8 MB
    int* ew   = (int*)w;  w += (size_t)N_EDGES * 4;          // 6.4 MB
    int* cnt  = (int*)w;  w += (size_t)N_NODES * 4;
    int* off  = (int*)w;  w += ((size_t)(N_NODES + 1) * 4 + 12) & ~15ull;
    int* bsum = (int*)w;  w += 4096;
    float* dinv = (float*)w; w += (size_t)N_NODES * 4;
    u16* W1T = (u16*)w; w += (size_t)IN_DIM * HIDDEN * 2;
    u16* W2T = (u16*)w; w += (size_t)HIDDEN * EMBED * 2;

    // transient binning storage aliased onto x0bf+gA (dead until mlp_mfma runs)
    u32* slot    = (u32*)x0bf;                                       // 14.72 MB
    int* slotcnt = (int*)(x0bf + (size_t)NTILES * NBUCK * CAP * 2);  // after slots

    int nbN = (N_NODES + 255) / 256;

    conv_weights<<<(IN_DIM * HIDDEN + HIDDEN * EMBED + 255) / 256, 256, 0, stream>>>(W1, W2, W1T, W2T);
    zero_int<<<nbN, 256, 0, stream>>>(cnt, N_NODES);
    bin_edges<<<NTILES, 256, 0, stream>>>(row, col, slot, slotcnt, cnt, N_EDGES);
    calc_dinv<<<nbN, 256, 0, stream>>>(cnt, dinv, N_NODES);

    block_reduce<<<nbN, 256, 0, stream>>>(cnt, bsum, N_NODES);
    scan_blk<<<1, 512, 0, stream>>>(bsum, nbN);
    block_scan<<<nbN, 256, 0, stream>>>(cnt, bsum, off, N_NODES);
    set_tail<<<1, 1, 0, stream>>>(off);

    csc_from_bins<<<NBUCK, 1024, 0, stream>>>(slot, slotcnt, off, ew);

    // MLP after binning (slots alias x0bf/gA)
    mlp_mfma<<<(N_NODES + 31) / 32, 256, 0, stream>>>(x, W1T, b1, W2T, b2, dinv, x0bf, gA, N_NODES);

    // K=10 steps
    const u32* gin = (const u32*)gA;
    for (int s = 0; s < K_STEPS; ++s) {
        int fin = (s == K_STEPS - 1);
        u32* gout = (u32*)((s & 1) ? gA : gB);
        prop8<<<N_NODES / 32, 256, 0, stream>>>(off, ew, gin, (const u32*)x0bf, dinv,
                                                gout, out, fin);
        gin = gout;
    }
}

// Round 9
// 496.687 us; speedup vs baseline: 1.1212x; 1.0411x over previous
//
#include <hip/hip_runtime.h>

#define N_NODES 100000
#define N_EDGES 1600000
#define IN_DIM 128
#define HIDDEN 256
#define EMBED 64
#define K_STEPS 10

// binning geometry
#define NPB_SHIFT 10
#define NPB 1024                    // nodes per bucket
#define NBUCK 98                    // ceil(100000/1024)
#define TILE 2048                   // edges per bin tile
#define NTILES 782                  // ceil(1.6M/2048)
#define CAP 64                      // slots per (tile,bucket); mean 20.9, sigma 4.5 -> 9.6 sigma margin

typedef unsigned int u32;
typedef unsigned short u16;
using bf16x8 = __attribute__((ext_vector_type(8))) short;
using f32x4  = __attribute__((ext_vector_type(4))) float;

__device__ __forceinline__ float bflo(u32 u) { return __uint_as_float(u << 16); }
__device__ __forceinline__ float bfhi(u32 u) { return __uint_as_float(u & 0xffff0000u); }
__device__ __forceinline__ u16 f2bf(float f) {   // round-to-nearest-even
    u32 u = __float_as_uint(f);
    u += 0x7fffu + ((u >> 16) & 1u);
    return (u16)(u >> 16);
}

// ---------------- weight prep: transpose + bf16 convert ----------------
__global__ void conv_weights(const float* __restrict__ W1, const float* __restrict__ W2,
                             u16* __restrict__ W1T, u16* __restrict__ W2T)
{
    int i = blockIdx.x * 256 + threadIdx.x;
    if (i < IN_DIM * HIDDEN) {
        int n = i / IN_DIM, k = i % IN_DIM;
        W1T[i] = f2bf(W1[k * HIDDEN + n]);
    }
    int j = i - IN_DIM * HIDDEN;
    if (j >= 0 && j < HIDDEN * EMBED) {
        int n = j / HIDDEN, k = j % HIDDEN;
        W2T[j] = f2bf(W2[k * EMBED + n]);
    }
}

// ---------------- fused MLP via bf16 MFMA; 32-row tile (R8 version, unchanged) ----------------
__global__ __launch_bounds__(256, 6) void mlp_mfma(
    const float* __restrict__ x, const u16* __restrict__ W1T,
    const float* __restrict__ b1, const u16* __restrict__ W2T,
    const float* __restrict__ b2, const float* __restrict__ dinv,
    u16* __restrict__ x0bf, u16* __restrict__ g0bf, int n)
{
    __shared__ u16 Xs[32][136];    // 8.7 KB
    __shared__ u16 H1s[32][264];   // 16.9 KB
    int t = threadIdx.x;
    int rowBase = blockIdx.x * 32;
    int lane = t & 63, w = t >> 6;
    int lr = lane & 15, kg = lane >> 4;

    for (int i = t; i < 32 * 32; i += 256) {
        int row = i >> 5, c4 = (i & 31) * 4;
        float4 v = make_float4(0.f, 0.f, 0.f, 0.f);
        if (rowBase + row < n) v = *(const float4*)(x + (size_t)(rowBase + row) * IN_DIM + c4);
        Xs[row][c4 + 0] = f2bf(v.x); Xs[row][c4 + 1] = f2bf(v.y);
        Xs[row][c4 + 2] = f2bf(v.z); Xs[row][c4 + 3] = f2bf(v.w);
    }
    __syncthreads();

    { // phase 1: H1[32][256] = relu(X@W1+b1); wave w owns cols w*64..+63
        int n0 = w * 64;
        f32x4 acc[2][4];
        #pragma unroll
        for (int m = 0; m < 2; ++m)
            #pragma unroll
            for (int nn = 0; nn < 4; ++nn) acc[m][nn] = (f32x4){0.f, 0.f, 0.f, 0.f};
        #pragma unroll
        for (int k0 = 0; k0 < IN_DIM; k0 += 32) {
            bf16x8 a[2], b[4];
            #pragma unroll
            for (int m = 0; m < 2; ++m) a[m] = *(const bf16x8*)&Xs[m * 16 + lr][k0 + kg * 8];
            #pragma unroll
            for (int nn = 0; nn < 4; ++nn)
                b[nn] = *(const bf16x8*)(W1T + (size_t)(n0 + nn * 16 + lr) * IN_DIM + k0 + kg * 8);
            #pragma unroll
            for (int m = 0; m < 2; ++m)
                #pragma unroll
                for (int nn = 0; nn < 4; ++nn)
                    acc[m][nn] = __builtin_amdgcn_mfma_f32_16x16x32_bf16(a[m], b[nn], acc[m][nn], 0, 0, 0);
        }
        #pragma unroll
        for (int nn = 0; nn < 4; ++nn) {
            float bb = b1[n0 + nn * 16 + lr];
            #pragma unroll
            for (int m = 0; m < 2; ++m)
                #pragma unroll
                for (int r = 0; r < 4; ++r)
                    H1s[m * 16 + kg * 4 + r][n0 + nn * 16 + lr] = f2bf(fmaxf(acc[m][nn][r] + bb, 0.f));
        }
    }
    __syncthreads();

    { // phase 2: H0[32][64] = H1@W2+b2; wave w: rows (w&1)*16, cols (w>>1)*32
        int r0 = (w & 1) * 16, c0 = (w >> 1) * 32;
        f32x4 acc[2];
        #pragma unroll
        for (int nn = 0; nn < 2; ++nn) acc[nn] = (f32x4){0.f, 0.f, 0.f, 0.f};
        #pragma unroll
        for (int k0 = 0; k0 < HIDDEN; k0 += 32) {
            bf16x8 a = *(const bf16x8*)&H1s[r0 + lr][k0 + kg * 8];
            #pragma unroll
            for (int nn = 0; nn < 2; ++nn) {
                bf16x8 b = *(const bf16x8*)(W2T + (size_t)(c0 + nn * 16 + lr) * HIDDEN + k0 + kg * 8);
                acc[nn] = __builtin_amdgcn_mfma_f32_16x16x32_bf16(a, b, acc[nn], 0, 0, 0);
            }
        }
        #pragma unroll
        for (int nn = 0; nn < 2; ++nn) {
            float bb = b2[c0 + nn * 16 + lr];
            #pragma unroll
            for (int r = 0; r < 4; ++r) {
                int rw = rowBase + r0 + kg * 4 + r;
                if (rw < n) {
                    float val = acc[nn][r] + bb;
                    size_t idx = (size_t)rw * EMBED + c0 + nn * 16 + lr;
                    x0bf[idx] = f2bf(val);
                    g0bf[idx] = f2bf(dinv[rw] * val);
                }
            }
        }
    }
}

// ---- pass B: bin edges by dst bucket into tile-private slots (LDS cursors, NO device atomics) ----
__global__ __launch_bounds__(256) void bin_edges(
    const int* __restrict__ row, const int* __restrict__ col,
    u32* __restrict__ slot, int* __restrict__ slotcnt, int e)
{
    __shared__ int bcur[NBUCK];
    int t = threadIdx.x;
    if (t < NBUCK) bcur[t] = 0;
    __syncthreads();
    int base = blockIdx.x * TILE;
    for (int i = t; i < TILE; i += 256) {
        int gi = base + i;
        if (gi >= e) break;
        int c = col[gi], r = row[gi];
        int b = c >> NPB_SHIFT;
        int pos = atomicAdd(&bcur[b], 1);
        if (pos < CAP)
            slot[((size_t)blockIdx.x * NBUCK + b) * CAP + pos] =
                (u32)r | ((u32)(c & (NPB - 1)) << 17);
    }
    __syncthreads();
    if (t < NBUCK) slotcnt[blockIdx.x * NBUCK + t] = min(bcur[t], CAP);
}

// ---- bucket-level exclusive scan (98 buckets) + off tail ----
__global__ void scan_buckets(const int* __restrict__ slotcnt,
                             int* __restrict__ bucket_base, int* __restrict__ off)
{
    __shared__ int s[NBUCK];
    int t = threadIdx.x;   // 128 threads
    if (t < NBUCK) {
        int sum = 0;
        for (int tile = 0; tile < NTILES; ++tile) sum += slotcnt[tile * NBUCK + t];
        s[t] = sum;
    }
    __syncthreads();
    if (t == 0) {
        int run = 0;
        for (int b = 0; b < NBUCK; ++b) { bucket_base[b] = run; run += s[b]; }
        off[N_NODES] = run;
    }
}

// ---- pass C: count (LDS) -> scan (LDS) -> off/dinv -> place exact CSC ----
__global__ __launch_bounds__(1024) void csc_from_bins(
    const u32* __restrict__ slot, const int* __restrict__ slotcnt,
    const int* __restrict__ bucket_base,
    int* __restrict__ off, float* __restrict__ dinv, int* __restrict__ ew)
{
    __shared__ int cnt[NPB];
    __shared__ int sA[NPB];
    __shared__ int sB[NPB];
    int b = blockIdx.x, t = threadIdx.x;
    int vbase = b << NPB_SHIFT;
    int nv = min(NPB, N_NODES - vbase);
    int wid = t >> 6, lane = t & 63;

    cnt[t] = 0;
    __syncthreads();
    // pass A: count per-node degree from slot entries (LDS atomics on 1024 counters)
    for (int tile = wid; tile < NTILES; tile += 16) {
        int n_tb = slotcnt[tile * NBUCK + b];
        const u32* seg = slot + ((size_t)tile * NBUCK + b) * CAP;
        for (int i = lane; i < n_tb; i += 64)
            atomicAdd(&cnt[seg[i] >> 17], 1);
    }
    __syncthreads();
    sA[t] = cnt[t];
    __syncthreads();
    // inclusive Hillis-Steele scan over 1024 (1 elem/thread, ping-pong)
    int* src = sA; int* dst = sB;
    #pragma unroll
    for (int o = 1; o < NPB; o <<= 1) {
        dst[t] = src[t] + ((t >= o) ? src[t - o] : 0);
        __syncthreads();
        int* tmp = src; src = dst; dst = tmp;
    }
    int bb = bucket_base[b];
    int c  = cnt[t];
    int o  = bb + src[t] - c;   // exclusive offset
    if (t < nv) {
        off[vbase + t]  = o;
        dinv[vbase + t] = rsqrtf((float)(c + 1));
    }
    __syncthreads();
    cnt[t] = o;                 // cnt becomes cursor
    __syncthreads();
    // pass B: place edges
    for (int tile = wid; tile < NTILES; tile += 16) {
        int n_tb = slotcnt[tile * NBUCK + b];
        const u32* seg = slot + ((size_t)tile * NBUCK + b) * CAP;
        for (int i = lane; i < n_tb; i += 64) {
            u32 u = seg[i];
            int p = atomicAdd(&cnt[u >> 17], 1);
            ew[p] = (int)(u & 0x1FFFFu);
        }
    }
}

// ---------------- propagation: pull, 8 lanes/node x 16B/lane, unroll x4 (proven) ----------------
__global__ __launch_bounds__(256) void prop8(
    const int* __restrict__ off, const int* __restrict__ ew,
    const u32* __restrict__ gin, const u32* __restrict__ x0,
    const float* __restrict__ dinv,
    u32* __restrict__ gout, float* __restrict__ hout, int final_step)
{
    int t = threadIdx.x;
    int v = blockIdx.x * 32 + (t >> 3);
    int l = t & 7;
    const u32* base = gin + l * 4;
    int s = off[v], e = off[v + 1];

    float aL0 = 0.f, aH0 = 0.f, aL1 = 0.f, aH1 = 0.f;
    float aL2 = 0.f, aH2 = 0.f, aL3 = 0.f, aH3 = 0.f;

    int i = s;
    int pre = (4 - (s & 3)) & 3;
    if (pre > e - s) pre = e - s;
    for (int k = 0; k < pre; ++k, ++i) {
        uint4 r = *(const uint4*)(base + (size_t)ew[i] * 32);
        aL0 += bflo(r.x); aH0 += bfhi(r.x);
        aL1 += bflo(r.y); aH1 += bfhi(r.y);
        aL2 += bflo(r.z); aH2 += bfhi(r.z);
        aL3 += bflo(r.w); aH3 += bfhi(r.w);
    }
    for (; i + 4 <= e; i += 4) {
        int4 e4 = *(const int4*)(ew + i);
        uint4 r0 = *(const uint4*)(base + (size_t)e4.x * 32);
        uint4 r1 = *(const uint4*)(base + (size_t)e4.y * 32);
        uint4 r2 = *(const uint4*)(base + (size_t)e4.z * 32);
        uint4 r3 = *(const uint4*)(base + (size_t)e4.w * 32);
        aL0 += (bflo(r0.x) + bflo(r1.x)) + (bflo(r2.x) + bflo(r3.x));
        aH0 += (bfhi(r0.x) + bfhi(r1.x)) + (bfhi(r2.x) + bfhi(r3.x));
        aL1 += (bflo(r0.y) + bflo(r1.y)) + (bflo(r2.y) + bflo(r3.y));
        aH1 += (bfhi(r0.y) + bfhi(r1.y)) + (bfhi(r2.y) + bfhi(r3.y));
        aL2 += (bflo(r0.z) + bflo(r1.z)) + (bflo(r2.z) + bflo(r3.z));
        aH2 += (bfhi(r0.z) + bfhi(r1.z)) + (bfhi(r2.z) + bfhi(r3.z));
        aL3 += (bflo(r0.w) + bflo(r1.w)) + (bflo(r2.w) + bflo(r3.w));
        aH3 += (bfhi(r0.w) + bfhi(r1.w)) + (bfhi(r2.w) + bfhi(r3.w));
    }
    for (; i < e; ++i) {
        uint4 r = *(const uint4*)(base + (size_t)ew[i] * 32);
        aL0 += bflo(r.x); aH0 += bfhi(r.x);
        aL1 += bflo(r.y); aH1 += bfhi(r.y);
        aL2 += bflo(r.z); aH2 += bfhi(r.z);
        aL3 += bflo(r.w); aH3 += bfhi(r.w);
    }

    uint4 rs = *(const uint4*)(base + (size_t)v * 32);
    uint4 rx = *(const uint4*)(x0 + (size_t)v * 32 + l * 4);
    float dv = dinv[v];
    float h0 = 0.9f * dv * (aL0 + bflo(rs.x)) + 0.1f * bflo(rx.x);
    float h1 = 0.9f * dv * (aH0 + bfhi(rs.x)) + 0.1f * bfhi(rx.x);
    float h2 = 0.9f * dv * (aL1 + bflo(rs.y)) + 0.1f * bflo(rx.y);
    float h3 = 0.9f * dv * (aH1 + bfhi(rs.y)) + 0.1f * bfhi(rx.y);
    float h4 = 0.9f * dv * (aL2 + bflo(rs.z)) + 0.1f * bflo(rx.z);
    float h5 = 0.9f * dv * (aH2 + bfhi(rs.z)) + 0.1f * bfhi(rx.z);
    float h6 = 0.9f * dv * (aL3 + bflo(rs.w)) + 0.1f * bflo(rx.w);
    float h7 = 0.9f * dv * (aH3 + bfhi(rs.w)) + 0.1f * bfhi(rx.w);

    if (final_step) {
        float* o = hout + (size_t)v * EMBED + l * 8;
        *(float4*)(o)     = make_float4(h0, h1, h2, h3);
        *(float4*)(o + 4) = make_float4(h4, h5, h6, h7);
    } else {
        uint4 g;
        g.x = (u32)f2bf(dv * h0) | ((u32)f2bf(dv * h1) << 16);
        g.y = (u32)f2bf(dv * h2) | ((u32)f2bf(dv * h3) << 16);
        g.z = (u32)f2bf(dv * h4) | ((u32)f2bf(dv * h5) << 16);
        g.w = (u32)f2bf(dv * h6) | ((u32)f2bf(dv * h7) << 16);
        *(uint4*)(gout + (size_t)v * 32 + l * 4) = g;
    }
}

extern "C" void kernel_launch(void* const* d_in, const int* in_sizes, int n_in,
                              void* d_out, int out_size, void* d_ws, size_t ws_size,
                              hipStream_t stream)
{
    const float* x  = (const float*)d_in[0];
    const int*   ei = (const int*)d_in[1];
    const float* W1 = (const float*)d_in[2];
    const float* b1 = (const float*)d_in[3];
    const float* W2 = (const float*)d_in[4];
    const float* b2 = (const float*)d_in[5];
    float* out = (float*)d_out;
    const int* row = ei;
    const int* col = ei + N_EDGES;

    // permanent carve-out (~46 MB)
    char* w = (char*)d_ws;
    u16* x0bf = (u16*)w; w += (size_t)N_NODES * EMBED * 2;   // 12.8 MB
    u16* gA   = (u16*)w; w += (size_t)N_NODES * EMBED * 2;   // 12.8 MB (x0bf+gA = 25.6 MB alias region)
    u16* gB   = (u16*)w; w += (size_t)N_NODES * EMBED * 2;   // 12.8 MB
    int* ew   = (int*)w;  w += (size_t)N_EDGES * 4;          // 6.4 MB
    int* off  = (int*)w;  w += ((size_t)(N_NODES + 1) * 4 + 12) & ~15ull;
    int* bucket_base = (int*)w; w += 4096;
    float* dinv = (float*)w; w += (size_t)N_NODES * 4;
    u16* W1T = (u16*)w; w += (size_t)IN_DIM * HIDDEN * 2;
    u16* W2T = (u16*)w; w += (size_t)HIDDEN * EMBED * 2;

    // transient binning storage aliased onto x0bf+gA (dead until mlp_mfma runs)
    u32* slot    = (u32*)x0bf;                                     // 782*98*64*4 = 19.62 MB
    int* slotcnt = (int*)((char*)x0bf + (size_t)NTILES * NBUCK * CAP * 4);  // +306 KB = 19.93 MB total

    conv_weights<<<(IN_DIM * HIDDEN + HIDDEN * EMBED + 255) / 256, 256, 0, stream>>>(W1, W2, W1T, W2T);
    bin_edges<<<NTILES, 256, 0, stream>>>(row, col, slot, slotcnt, N_EDGES);
    scan_buckets<<<1, 128, 0, stream>>>(slotcnt, bucket_base, off);
    csc_from_bins<<<NBUCK, 1024, 0, stream>>>(slot, slotcnt, bucket_base, off, dinv, ew);

    // MLP after binning (slots alias x0bf/gA); needs dinv (from csc_from_bins)
    mlp_mfma<<<(N_NODES + 31) / 32, 256, 0, stream>>>(x, W1T, b1, W2T, b2, dinv, x0bf, gA, N_NODES);

    // K=10 steps
    const u32* gin = (const u32*)gA;
    for (int s = 0; s < K_STEPS; ++s) {
        int fin = (s == K_STEPS - 1);
        u32* gout = (u32*)((s & 1) ? gA : gB);
        prop8<<<N_NODES / 32, 256, 0, stream>>>(off, ew, gin, (const u32*)x0bf, dinv,
                                                gout, out, fin);
        gin = gout;
    }
}

// Round 10
// 470.605 us; speedup vs baseline: 1.1834x; 1.0554x over previous
//
#include <hip/hip_runtime.h>

#define N_NODES 100000
#define N_EDGES 1600000
#define IN_DIM 128
#define HIDDEN 256
#define EMBED 64
#define K_STEPS 10

// binning geometry
#define NPB_SHIFT 10
#define NPB 1024                    // nodes per bucket
#define NBUCK 98                    // ceil(100000/1024)
#define TILE 2048                   // edges per bin tile
#define NTILES 782                  // ceil(1.6M/2048)
#define CAP 64                      // slots per (tile,bucket); mean 20.9 -> 9.6 sigma margin

typedef unsigned int u32;
typedef unsigned short u16;
using bf16x8 = __attribute__((ext_vector_type(8))) short;
using f32x4  = __attribute__((ext_vector_type(4))) float;

__device__ __forceinline__ float bflo(u32 u) { return __uint_as_float(u << 16); }
__device__ __forceinline__ float bfhi(u32 u) { return __uint_as_float(u & 0xffff0000u); }
__device__ __forceinline__ u16 f2bf(float f) {   // round-to-nearest-even
    u32 u = __float_as_uint(f);
    u += 0x7fffu + ((u >> 16) & 1u);
    return (u16)(u >> 16);
}

// ---------------- weight prep: transpose + bf16 convert ----------------
__global__ void conv_weights(const float* __restrict__ W1, const float* __restrict__ W2,
                             u16* __restrict__ W1T, u16* __restrict__ W2T)
{
    int i = blockIdx.x * 256 + threadIdx.x;
    if (i < IN_DIM * HIDDEN) {
        int n = i / IN_DIM, k = i % IN_DIM;
        W1T[i] = f2bf(W1[k * HIDDEN + n]);
    }
    int j = i - IN_DIM * HIDDEN;
    if (j >= 0 && j < HIDDEN * EMBED) {
        int n = j / HIDDEN, k = j % HIDDEN;
        W2T[j] = f2bf(W2[k * EMBED + n]);
    }
}

// ---------------- fused MLP via bf16 MFMA; 32-row tile, VGPRs unconstrained ----------------
__global__ __launch_bounds__(256) void mlp_mfma(
    const float* __restrict__ x, const u16* __restrict__ W1T,
    const float* __restrict__ b1, const u16* __restrict__ W2T,
    const float* __restrict__ b2, const float* __restrict__ dinv,
    u16* __restrict__ x0bf, u16* __restrict__ g0bf, int n)
{
    __shared__ u16 Xs[32][136];    // 8.7 KB
    __shared__ u16 H1s[32][264];   // 16.9 KB  (25.6 KB total -> 6 blocks/CU by LDS)
    int t = threadIdx.x;
    int rowBase = blockIdx.x * 32;
    int lane = t & 63, w = t >> 6;
    int lr = lane & 15, kg = lane >> 4;

    for (int i = t; i < 32 * 32; i += 256) {
        int row = i >> 5, c4 = (i & 31) * 4;
        float4 v = make_float4(0.f, 0.f, 0.f, 0.f);
        if (rowBase + row < n) v = *(const float4*)(x + (size_t)(rowBase + row) * IN_DIM + c4);
        Xs[row][c4 + 0] = f2bf(v.x); Xs[row][c4 + 1] = f2bf(v.y);
        Xs[row][c4 + 2] = f2bf(v.z); Xs[row][c4 + 3] = f2bf(v.w);
    }
    __syncthreads();

    { // phase 1: H1[32][256] = relu(X@W1+b1); wave w owns cols w*64..+63
        int n0 = w * 64;
        f32x4 acc[2][4];
        #pragma unroll
        for (int m = 0; m < 2; ++m)
            #pragma unroll
            for (int nn = 0; nn < 4; ++nn) acc[m][nn] = (f32x4){0.f, 0.f, 0.f, 0.f};
        #pragma unroll
        for (int k0 = 0; k0 < IN_DIM; k0 += 32) {
            bf16x8 a[2], b[4];
            #pragma unroll
            for (int m = 0; m < 2; ++m) a[m] = *(const bf16x8*)&Xs[m * 16 + lr][k0 + kg * 8];
            #pragma unroll
            for (int nn = 0; nn < 4; ++nn)
                b[nn] = *(const bf16x8*)(W1T + (size_t)(n0 + nn * 16 + lr) * IN_DIM + k0 + kg * 8);
            #pragma unroll
            for (int m = 0; m < 2; ++m)
                #pragma unroll
                for (int nn = 0; nn < 4; ++nn)
                    acc[m][nn] = __builtin_amdgcn_mfma_f32_16x16x32_bf16(a[m], b[nn], acc[m][nn], 0, 0, 0);
        }
        #pragma unroll
        for (int nn = 0; nn < 4; ++nn) {
            float bb = b1[n0 + nn * 16 + lr];
            #pragma unroll
            for (int m = 0; m < 2; ++m)
                #pragma unroll
                for (int r = 0; r < 4; ++r)
                    H1s[m * 16 + kg * 4 + r][n0 + nn * 16 + lr] = f2bf(fmaxf(acc[m][nn][r] + bb, 0.f));
        }
    }
    __syncthreads();

    { // phase 2: H0[32][64] = H1@W2+b2; wave w: rows (w&1)*16, cols (w>>1)*32
        int r0 = (w & 1) * 16, c0 = (w >> 1) * 32;
        f32x4 acc[2];
        #pragma unroll
        for (int nn = 0; nn < 2; ++nn) acc[nn] = (f32x4){0.f, 0.f, 0.f, 0.f};
        #pragma unroll
        for (int k0 = 0; k0 < HIDDEN; k0 += 32) {
            bf16x8 a = *(const bf16x8*)&H1s[r0 + lr][k0 + kg * 8];
            #pragma unroll
            for (int nn = 0; nn < 2; ++nn) {
                bf16x8 b = *(const bf16x8*)(W2T + (size_t)(c0 + nn * 16 + lr) * HIDDEN + k0 + kg * 8);
                acc[nn] = __builtin_amdgcn_mfma_f32_16x16x32_bf16(a, b, acc[nn], 0, 0, 0);
            }
        }
        #pragma unroll
        for (int nn = 0; nn < 2; ++nn) {
            float bb = b2[c0 + nn * 16 + lr];
            #pragma unroll
            for (int r = 0; r < 4; ++r) {
                int rw = rowBase + r0 + kg * 4 + r;
                if (rw < n) {
                    float val = acc[nn][r] + bb;
                    size_t idx = (size_t)rw * EMBED + c0 + nn * 16 + lr;
                    x0bf[idx] = f2bf(val);
                    g0bf[idx] = f2bf(dinv[rw] * val);
                }
            }
        }
    }
}

// ---- pass B: bin edges by dst bucket into tile-private slots (LDS cursors only) ----
__global__ __launch_bounds__(256) void bin_edges(
    const int* __restrict__ row, const int* __restrict__ col,
    u32* __restrict__ slot, int* __restrict__ slotcnt, int e)
{
    __shared__ int bcur[NBUCK];
    int t = threadIdx.x;
    if (t < NBUCK) bcur[t] = 0;
    __syncthreads();
    int base = blockIdx.x * TILE;
    for (int i = t; i < TILE; i += 256) {
        int gi = base + i;
        if (gi >= e) break;
        int c = col[gi], r = row[gi];
        int b = c >> NPB_SHIFT;
        int pos = atomicAdd(&bcur[b], 1);
        if (pos < CAP)
            slot[((size_t)blockIdx.x * NBUCK + b) * CAP + pos] =
                (u32)r | ((u32)(c & (NPB - 1)) << 17);
    }
    __syncthreads();
    if (t < NBUCK) slotcnt[blockIdx.x * NBUCK + t] = min(bcur[t], CAP);
}

// ---- per-bucket tile-count reduction (98 blocks x 256 thr, parallel over tiles) ----
__global__ __launch_bounds__(256) void bucket_sums(const int* __restrict__ slotcnt,
                                                   int* __restrict__ bsum)
{
    __shared__ int sh[256];
    int b = blockIdx.x, t = threadIdx.x;
    int s = 0;
    for (int tile = t; tile < NTILES; tile += 256) s += slotcnt[tile * NBUCK + b];
    sh[t] = s; __syncthreads();
    for (int o = 128; o > 0; o >>= 1) {
        if (t < o) sh[t] += sh[t + o];
        __syncthreads();
    }
    if (t == 0) bsum[b] = sh[0];
}
// ---- tiny exclusive scan over 98 bucket sums ----
__global__ void scan_bucket_base(const int* __restrict__ bsum,
                                 int* __restrict__ bucket_base, int* __restrict__ off)
{
    if (threadIdx.x == 0) {
        int run = 0;
        for (int b = 0; b < NBUCK; ++b) { bucket_base[b] = run; run += bsum[b]; }
        off[N_NODES] = run;
    }
}

// ---- pass C: count (LDS) -> scan (LDS) -> off/dinv -> place exact CSC ----
__global__ __launch_bounds__(1024) void csc_from_bins(
    const u32* __restrict__ slot, const int* __restrict__ slotcnt,
    const int* __restrict__ bucket_base,
    int* __restrict__ off, float* __restrict__ dinv, int* __restrict__ ew)
{
    __shared__ int cnt[NPB];
    __shared__ int sA[NPB];
    __shared__ int sB[NPB];
    int b = blockIdx.x, t = threadIdx.x;
    int vbase = b << NPB_SHIFT;
    int nv = min(NPB, N_NODES - vbase);
    int wid = t >> 6, lane = t & 63;

    cnt[t] = 0;
    __syncthreads();
    for (int tile = wid; tile < NTILES; tile += 16) {
        int n_tb = slotcnt[tile * NBUCK + b];
        const u32* seg = slot + ((size_t)tile * NBUCK + b) * CAP;
        for (int i = lane; i < n_tb; i += 64)
            atomicAdd(&cnt[seg[i] >> 17], 1);
    }
    __syncthreads();
    sA[t] = cnt[t];
    __syncthreads();
    int* src = sA; int* dst = sB;
    #pragma unroll
    for (int o = 1; o < NPB; o <<= 1) {
        dst[t] = src[t] + ((t >= o) ? src[t - o] : 0);
        __syncthreads();
        int* tmp = src; src = dst; dst = tmp;
    }
    int bb = bucket_base[b];
    int c  = cnt[t];
    int o  = bb + src[t] - c;   // exclusive offset
    if (t < nv) {
        off[vbase + t]  = o;
        dinv[vbase + t] = rsqrtf((float)(c + 1));
    }
    __syncthreads();
    cnt[t] = o;                 // cnt becomes cursor
    __syncthreads();
    for (int tile = wid; tile < NTILES; tile += 16) {
        int n_tb = slotcnt[tile * NBUCK + b];
        const u32* seg = slot + ((size_t)tile * NBUCK + b) * CAP;
        for (int i = lane; i < n_tb; i += 64) {
            u32 u = seg[i];
            int p = atomicAdd(&cnt[u >> 17], 1);
            ew[p] = (int)(u & 0x1FFFFu);
        }
    }
}

// ---------------- propagation: pull, 8 lanes/node x 16B/lane, unroll x4 (proven) ----------------
__global__ __launch_bounds__(256) void prop8(
    const int* __restrict__ off, const int* __restrict__ ew,
    const u32* __restrict__ gin, const u32* __restrict__ x0,
    const float* __restrict__ dinv,
    u32* __restrict__ gout, float* __restrict__ hout, int final_step)
{
    int t = threadIdx.x;
    int v = blockIdx.x * 32 + (t >> 3);
    int l = t & 7;
    const u32* base = gin + l * 4;
    int s = off[v], e = off[v + 1];

    float aL0 = 0.f, aH0 = 0.f, aL1 = 0.f, aH1 = 0.f;
    float aL2 = 0.f, aH2 = 0.f, aL3 = 0.f, aH3 = 0.f;

    int i = s;
    int pre = (4 - (s & 3)) & 3;
    if (pre > e - s) pre = e - s;
    for (int k = 0; k < pre; ++k, ++i) {
        uint4 r = *(const uint4*)(base + (size_t)ew[i] * 32);
        aL0 += bflo(r.x); aH0 += bfhi(r.x);
        aL1 += bflo(r.y); aH1 += bfhi(r.y);
        aL2 += bflo(r.z); aH2 += bfhi(r.z);
        aL3 += bflo(r.w); aH3 += bfhi(r.w);
    }
    for (; i + 4 <= e; i += 4) {
        int4 e4 = *(const int4*)(ew + i);
        uint4 r0 = *(const uint4*)(base + (size_t)e4.x * 32);
        uint4 r1 = *(const uint4*)(base + (size_t)e4.y * 32);
        uint4 r2 = *(const uint4*)(base + (size_t)e4.z * 32);
        uint4 r3 = *(const uint4*)(base + (size_t)e4.w * 32);
        aL0 += (bflo(r0.x) + bflo(r1.x)) + (bflo(r2.x) + bflo(r3.x));
        aH0 += (bfhi(r0.x) + bfhi(r1.x)) + (bfhi(r2.x) + bfhi(r3.x));
        aL1 += (bflo(r0.y) + bflo(r1.y)) + (bflo(r2.y) + bflo(r3.y));
        aH1 += (bfhi(r0.y) + bfhi(r1.y)) + (bfhi(r2.y) + bfhi(r3.y));
        aL2 += (bflo(r0.z) + bflo(r1.z)) + (bflo(r2.z) + bflo(r3.z));
        aH2 += (bfhi(r0.z) + bfhi(r1.z)) + (bfhi(r2.z) + bfhi(r3.z));
        aL3 += (bflo(r0.w) + bflo(r1.w)) + (bflo(r2.w) + bflo(r3.w));
        aH3 += (bfhi(r0.w) + bfhi(r1.w)) + (bfhi(r2.w) + bfhi(r3.w));
    }
    for (; i < e; ++i) {
        uint4 r = *(const uint4*)(base + (size_t)ew[i] * 32);
        aL0 += bflo(r.x); aH0 += bfhi(r.x);
        aL1 += bflo(r.y); aH1 += bfhi(r.y);
        aL2 += bflo(r.z); aH2 += bfhi(r.z);
        aL3 += bflo(r.w); aH3 += bfhi(r.w);
    }

    uint4 rs = *(const uint4*)(base + (size_t)v * 32);
    uint4 rx = *(const uint4*)(x0 + (size_t)v * 32 + l * 4);
    float dv = dinv[v];
    float h0 = 0.9f * dv * (aL0 + bflo(rs.x)) + 0.1f * bflo(rx.x);
    float h1 = 0.9f * dv * (aH0 + bfhi(rs.x)) + 0.1f * bfhi(rx.x);
    float h2 = 0.9f * dv * (aL1 + bflo(rs.y)) + 0.1f * bflo(rx.y);
    float h3 = 0.9f * dv * (aH1 + bfhi(rs.y)) + 0.1f * bfhi(rx.y);
    float h4 = 0.9f * dv * (aL2 + bflo(rs.z)) + 0.1f * bflo(rx.z);
    float h5 = 0.9f * dv * (aH2 + bfhi(rs.z)) + 0.1f * bfhi(rx.z);
    float h6 = 0.9f * dv * (aL3 + bflo(rs.w)) + 0.1f * bflo(rx.w);
    float h7 = 0.9f * dv * (aH3 + bfhi(rs.w)) + 0.1f * bfhi(rx.w);

    if (final_step) {
        float* o = hout + (size_t)v * EMBED + l * 8;
        *(float4*)(o)     = make_float4(h0, h1, h2, h3);
        *(float4*)(o + 4) = make_float4(h4, h5, h6, h7);
    } else {
        uint4 g;
        g.x = (u32)f2bf(dv * h0) | ((u32)f2bf(dv * h1) << 16);
        g.y = (u32)f2bf(dv * h2) | ((u32)f2bf(dv * h3) << 16);
        g.z = (u32)f2bf(dv * h4) | ((u32)f2bf(dv * h5) << 16);
        g.w = (u32)f2bf(dv * h6) | ((u32)f2bf(dv * h7) << 16);
        *(uint4*)(gout + (size_t)v * 32 + l * 4) = g;
    }
}

extern "C" void kernel_launch(void* const* d_in, const int* in_sizes, int n_in,
                              void* d_out, int out_size, void* d_ws, size_t ws_size,
                              hipStream_t stream)
{
    const float* x  = (const float*)d_in[0];
    const int*   ei = (const int*)d_in[1];
    const float* W1 = (const float*)d_in[2];
    const float* b1 = (const float*)d_in[3];
    const float* W2 = (const float*)d_in[4];
    const float* b2 = (const float*)d_in[5];
    float* out = (float*)d_out;
    const int* row = ei;
    const int* col = ei + N_EDGES;

    // permanent carve-out (~46 MB)
    char* w = (char*)d_ws;
    u16* x0bf = (u16*)w; w += (size_t)N_NODES * EMBED * 2;   // 12.8 MB
    u16* gA   = (u16*)w; w += (size_t)N_NODES * EMBED * 2;   // 12.8 MB (x0bf+gA = alias region)
    u16* gB   = (u16*)w; w += (size_t)N_NODES * EMBED * 2;   // 12.8 MB
    int* ew   = (int*)w;  w += (size_t)N_EDGES * 4;          // 6.4 MB
    int* off  = (int*)w;  w += ((size_t)(N_NODES + 1) * 4 + 12) & ~15ull;
    int* bucket_base = (int*)w; w += 2048;
    int* bsum = (int*)w; w += 2048;
    float* dinv = (float*)w; w += (size_t)N_NODES * 4;
    u16* W1T = (u16*)w; w += (size_t)IN_DIM * HIDDEN * 2;
    u16* W2T = (u16*)w; w += (size_t)HIDDEN * EMBED * 2;

    // transient binning storage aliased onto x0bf+gA (dead until mlp_mfma runs)
    u32* slot    = (u32*)x0bf;                                     // 19.62 MB
    int* slotcnt = (int*)((char*)x0bf + (size_t)NTILES * NBUCK * CAP * 4);  // +306 KB

    conv_weights<<<(IN_DIM * HIDDEN + HIDDEN * EMBED + 255) / 256, 256, 0, stream>>>(W1, W2, W1T, W2T);
    bin_edges<<<NTILES, 256, 0, stream>>>(row, col, slot, slotcnt, N_EDGES);
    bucket_sums<<<NBUCK, 256, 0, stream>>>(slotcnt, bsum);
    scan_bucket_base<<<1, 64, 0, stream>>>(bsum, bucket_base, off);
    csc_from_bins<<<NBUCK, 1024, 0, stream>>>(slot, slotcnt, bucket_base, off, dinv, ew);

    // MLP after binning (slots alias x0bf/gA); needs dinv (from csc_from_bins)
    mlp_mfma<<<(N_NODES + 31) / 32, 256, 0, stream>>>(x, W1T, b1, W2T, b2, dinv, x0bf, gA, N_NODES);

    // K=10 steps
    const u32* gin = (const u32*)gA;
    for (int s = 0; s < K_STEPS; ++s) {
        int fin = (s == K_STEPS - 1);
        u32* gout = (u32*)((s & 1) ? gA : gB);
        prop8<<<N_NODES / 32, 256, 0, stream>>>(off, ew, gin, (const u32*)x0bf, dinv,
                                                gout, out, fin);
        gin = gout;
    }
}

// Round 11
// 448.229 us; speedup vs baseline: 1.2425x; 1.0499x over previous
//
#include <hip/hip_runtime.h>

#define N_NODES 100000
#define N_EDGES 1600000
#define IN_DIM 128
#define HIDDEN 256
#define EMBED 64
#define K_STEPS 10

// binning geometry
#define NPB_SHIFT 10
#define NPB 1024                    // nodes per bucket
#define NBUCK 98                    // ceil(100000/1024)
#define TILE 2048                   // edges per bin tile
#define NTILES 782                  // ceil(1.6M/2048)
#define CAP 64                      // slots per (tile,bucket); mean 20.9 -> 9.6 sigma margin

typedef unsigned int u32;
typedef unsigned short u16;
using bf16x8 = __attribute__((ext_vector_type(8))) short;
using f32x4  = __attribute__((ext_vector_type(4))) float;

__device__ __forceinline__ float bflo(u32 u) { return __uint_as_float(u << 16); }
__device__ __forceinline__ float bfhi(u32 u) { return __uint_as_float(u & 0xffff0000u); }
__device__ __forceinline__ u16 f2bf(float f) {   // round-to-nearest-even
    u32 u = __float_as_uint(f);
    u += 0x7fffu + ((u >> 16) & 1u);
    return (u16)(u >> 16);
}

// ---------------- weight prep: transpose + bf16 convert ----------------
__global__ void conv_weights(const float* __restrict__ W1, const float* __restrict__ W2,
                             u16* __restrict__ W1T, u16* __restrict__ W2T)
{
    int i = blockIdx.x * 256 + threadIdx.x;
    if (i < IN_DIM * HIDDEN) {
        int n = i / IN_DIM, k = i % IN_DIM;
        W1T[i] = f2bf(W1[k * HIDDEN + n]);
    }
    int j = i - IN_DIM * HIDDEN;
    if (j >= 0 && j < HIDDEN * EMBED) {
        int n = j / HIDDEN, k = j % HIDDEN;
        W2T[j] = f2bf(W2[k * EMBED + n]);
    }
}

// ---------------- fused MLP via bf16 MFMA; 32-row tile, forced load-ILP ----------------
__global__ __launch_bounds__(256) void mlp_mfma(
    const float* __restrict__ x, const u16* __restrict__ W1T,
    const float* __restrict__ b1, const u16* __restrict__ W2T,
    const float* __restrict__ b2, const float* __restrict__ dinv,
    u16* __restrict__ x0bf, u16* __restrict__ g0bf, int n)
{
    __shared__ u16 Xs[32][136];    // 8.7 KB
    __shared__ u16 H1s[32][264];   // 16.9 KB  (25.6 KB total)
    int t = threadIdx.x;
    int rowBase = blockIdx.x * 32;
    int lane = t & 63, w = t >> 6;
    int lr = lane & 15, kg = lane >> 4;

    // ---- stage X tile: 4 independent loads, then 4 writes (4x outstanding) ----
    {
        float4 v[4];
        #pragma unroll
        for (int it = 0; it < 4; ++it) {
            int i = t + it * 256;
            int row = i >> 5, c4 = (i & 31) * 4;
            v[it] = make_float4(0.f, 0.f, 0.f, 0.f);
            if (rowBase + row < n)
                v[it] = *(const float4*)(x + (size_t)(rowBase + row) * IN_DIM + c4);
        }
        #pragma unroll
        for (int it = 0; it < 4; ++it) {
            int i = t + it * 256;
            int row = i >> 5, c4 = (i & 31) * 4;
            Xs[row][c4 + 0] = f2bf(v[it].x); Xs[row][c4 + 1] = f2bf(v[it].y);
            Xs[row][c4 + 2] = f2bf(v[it].z); Xs[row][c4 + 3] = f2bf(v[it].w);
        }
    }

    // ---- prefetch ALL phase-1 W fragments BEFORE the barrier (fly during barrier wait) ----
    int n0 = w * 64;
    bf16x8 ball[4][4];
    #pragma unroll
    for (int k = 0; k < 4; ++k)
        #pragma unroll
        for (int nn = 0; nn < 4; ++nn)
            ball[k][nn] = *(const bf16x8*)(W1T + (size_t)(n0 + nn * 16 + lr) * IN_DIM + k * 32 + kg * 8);
    __syncthreads();

    { // phase 1: H1[32][256] = relu(X@W1+b1); wave w owns cols w*64..+63
        f32x4 acc[2][4];
        #pragma unroll
        for (int m = 0; m < 2; ++m)
            #pragma unroll
            for (int nn = 0; nn < 4; ++nn) acc[m][nn] = (f32x4){0.f, 0.f, 0.f, 0.f};
        #pragma unroll
        for (int k = 0; k < 4; ++k) {
            bf16x8 a[2];
            a[0] = *(const bf16x8*)&Xs[lr][k * 32 + kg * 8];
            a[1] = *(const bf16x8*)&Xs[16 + lr][k * 32 + kg * 8];
            #pragma unroll
            for (int m = 0; m < 2; ++m)
                #pragma unroll
                for (int nn = 0; nn < 4; ++nn)
                    acc[m][nn] = __builtin_amdgcn_mfma_f32_16x16x32_bf16(a[m], ball[k][nn], acc[m][nn], 0, 0, 0);
        }
        #pragma unroll
        for (int nn = 0; nn < 4; ++nn) {
            float bb = b1[n0 + nn * 16 + lr];
            #pragma unroll
            for (int m = 0; m < 2; ++m)
                #pragma unroll
                for (int r = 0; r < 4; ++r)
                    H1s[m * 16 + kg * 4 + r][n0 + nn * 16 + lr] = f2bf(fmaxf(acc[m][nn][r] + bb, 0.f));
        }
    }

    // ---- prefetch ALL phase-2 W fragments BEFORE the barrier ----
    int r0 = (w & 1) * 16, c0 = (w >> 1) * 32;
    bf16x8 ball2[8][2];
    #pragma unroll
    for (int k = 0; k < 8; ++k)
        #pragma unroll
        for (int nn = 0; nn < 2; ++nn)
            ball2[k][nn] = *(const bf16x8*)(W2T + (size_t)(c0 + nn * 16 + lr) * HIDDEN + k * 32 + kg * 8);
    __syncthreads();

    { // phase 2: H0[32][64] = H1@W2+b2; wave w: rows (w&1)*16, cols (w>>1)*32
        f32x4 acc2[2];
        acc2[0] = (f32x4){0.f, 0.f, 0.f, 0.f};
        acc2[1] = (f32x4){0.f, 0.f, 0.f, 0.f};
        #pragma unroll
        for (int k = 0; k < 8; ++k) {
            bf16x8 a = *(const bf16x8*)&H1s[r0 + lr][k * 32 + kg * 8];
            acc2[0] = __builtin_amdgcn_mfma_f32_16x16x32_bf16(a, ball2[k][0], acc2[0], 0, 0, 0);
            acc2[1] = __builtin_amdgcn_mfma_f32_16x16x32_bf16(a, ball2[k][1], acc2[1], 0, 0, 0);
        }
        #pragma unroll
        for (int nn = 0; nn < 2; ++nn) {
            float bb = b2[c0 + nn * 16 + lr];
            #pragma unroll
            for (int r = 0; r < 4; ++r) {
                int rw = rowBase + r0 + kg * 4 + r;
                if (rw < n) {
                    float val = acc2[nn][r] + bb;
                    size_t idx = (size_t)rw * EMBED + c0 + nn * 16 + lr;
                    x0bf[idx] = f2bf(val);
                    g0bf[idx] = f2bf(dinv[rw] * val);
                }
            }
        }
    }
}

// ---- pass B: bin edges by dst bucket into tile-private slots (LDS cursors only) ----
__global__ __launch_bounds__(256) void bin_edges(
    const int* __restrict__ row, const int* __restrict__ col,
    u32* __restrict__ slot, int* __restrict__ slotcnt, int e)
{
    __shared__ int bcur[NBUCK];
    int t = threadIdx.x;
    if (t < NBUCK) bcur[t] = 0;
    __syncthreads();
    int base = blockIdx.x * TILE;
    for (int i = t; i < TILE; i += 256) {
        int gi = base + i;
        if (gi >= e) break;
        int c = col[gi], r = row[gi];
        int b = c >> NPB_SHIFT;
        int pos = atomicAdd(&bcur[b], 1);
        if (pos < CAP)
            slot[((size_t)blockIdx.x * NBUCK + b) * CAP + pos] =
                (u32)r | ((u32)(c & (NPB - 1)) << 17);
    }
    __syncthreads();
    if (t < NBUCK) slotcnt[blockIdx.x * NBUCK + t] = min(bcur[t], CAP);
}

// ---- per-bucket tile-count reduction (98 blocks x 256 thr) ----
__global__ __launch_bounds__(256) void bucket_sums(const int* __restrict__ slotcnt,
                                                   int* __restrict__ bsum)
{
    __shared__ int sh[256];
    int b = blockIdx.x, t = threadIdx.x;
    int s = 0;
    for (int tile = t; tile < NTILES; tile += 256) s += slotcnt[tile * NBUCK + b];
    sh[t] = s; __syncthreads();
    for (int o = 128; o > 0; o >>= 1) {
        if (t < o) sh[t] += sh[t + o];
        __syncthreads();
    }
    if (t == 0) bsum[b] = sh[0];
}
// ---- tiny exclusive scan over 98 bucket sums ----
__global__ void scan_bucket_base(const int* __restrict__ bsum,
                                 int* __restrict__ bucket_base, int* __restrict__ off)
{
    if (threadIdx.x == 0) {
        int run = 0;
        for (int b = 0; b < NBUCK; ++b) { bucket_base[b] = run; run += bsum[b]; }
        off[N_NODES] = run;
    }
}

// ---- pass C: count (LDS) -> scan (LDS) -> off/dinv -> place; 32-lane sub-wave drains ----
__global__ __launch_bounds__(1024) void csc_from_bins(
    const u32* __restrict__ slot, const int* __restrict__ slotcnt,
    const int* __restrict__ bucket_base,
    int* __restrict__ off, float* __restrict__ dinv, int* __restrict__ ew)
{
    __shared__ int cnt[NPB];
    __shared__ int sA[NPB];
    __shared__ int sB[NPB];
    int b = blockIdx.x, t = threadIdx.x;
    int vbase = b << NPB_SHIFT;
    int nv = min(NPB, N_NODES - vbase);
    int wid = t >> 5, lane = t & 31;   // 32 sub-groups of 32 lanes

    cnt[t] = 0;
    __syncthreads();
    for (int tile = wid; tile < NTILES; tile += 32) {
        int n_tb = slotcnt[tile * NBUCK + b];
        const u32* seg = slot + ((size_t)tile * NBUCK + b) * CAP;
        for (int i = lane; i < n_tb; i += 32)
            atomicAdd(&cnt[seg[i] >> 17], 1);
    }
    __syncthreads();
    sA[t] = cnt[t];
    __syncthreads();
    int* src = sA; int* dst = sB;
    #pragma unroll
    for (int o = 1; o < NPB; o <<= 1) {
        dst[t] = src[t] + ((t >= o) ? src[t - o] : 0);
        __syncthreads();
        int* tmp = src; src = dst; dst = tmp;
    }
    int bb = bucket_base[b];
    int c  = cnt[t];
    int o  = bb + src[t] - c;   // exclusive offset
    if (t < nv) {
        off[vbase + t]  = o;
        dinv[vbase + t] = rsqrtf((float)(c + 1));
    }
    __syncthreads();
    cnt[t] = o;                 // cnt becomes cursor
    __syncthreads();
    for (int tile = wid; tile < NTILES; tile += 32) {
        int n_tb = slotcnt[tile * NBUCK + b];
        const u32* seg = slot + ((size_t)tile * NBUCK + b) * CAP;
        for (int i = lane; i < n_tb; i += 32) {
            u32 u = seg[i];
            int p = atomicAdd(&cnt[u >> 17], 1);
            ew[p] = (int)(u & 0x1FFFFu);
        }
    }
}

// ---------------- propagation: pull, 8 lanes/node x 16B/lane, unroll x4 (proven) ----------------
__global__ __launch_bounds__(256) void prop8(
    const int* __restrict__ off, const int* __restrict__ ew,
    const u32* __restrict__ gin, const u32* __restrict__ x0,
    const float* __restrict__ dinv,
    u32* __restrict__ gout, float* __restrict__ hout, int final_step)
{
    int t = threadIdx.x;
    int v = blockIdx.x * 32 + (t >> 3);
    int l = t & 7;
    const u32* base = gin + l * 4;
    int s = off[v], e = off[v + 1];

    float aL0 = 0.f, aH0 = 0.f, aL1 = 0.f, aH1 = 0.f;
    float aL2 = 0.f, aH2 = 0.f, aL3 = 0.f, aH3 = 0.f;

    int i = s;
    int pre = (4 - (s & 3)) & 3;
    if (pre > e - s) pre = e - s;
    for (int k = 0; k < pre; ++k, ++i) {
        uint4 r = *(const uint4*)(base + (size_t)ew[i] * 32);
        aL0 += bflo(r.x); aH0 += bfhi(r.x);
        aL1 += bflo(r.y); aH1 += bfhi(r.y);
        aL2 += bflo(r.z); aH2 += bfhi(r.z);
        aL3 += bflo(r.w); aH3 += bfhi(r.w);
    }
    for (; i + 4 <= e; i += 4) {
        int4 e4 = *(const int4*)(ew + i);
        uint4 r0 = *(const uint4*)(base + (size_t)e4.x * 32);
        uint4 r1 = *(const uint4*)(base + (size_t)e4.y * 32);
        uint4 r2 = *(const uint4*)(base + (size_t)e4.z * 32);
        uint4 r3 = *(const uint4*)(base + (size_t)e4.w * 32);
        aL0 += (bflo(r0.x) + bflo(r1.x)) + (bflo(r2.x) + bflo(r3.x));
        aH0 += (bfhi(r0.x) + bfhi(r1.x)) + (bfhi(r2.x) + bfhi(r3.x));
        aL1 += (bflo(r0.y) + bflo(r1.y)) + (bflo(r2.y) + bflo(r3.y));
        aH1 += (bfhi(r0.y) + bfhi(r1.y)) + (bfhi(r2.y) + bfhi(r3.y));
        aL2 += (bflo(r0.z) + bflo(r1.z)) + (bflo(r2.z) + bflo(r3.z));
        aH2 += (bfhi(r0.z) + bfhi(r1.z)) + (bfhi(r2.z) + bfhi(r3.z));
        aL3 += (bflo(r0.w) + bflo(r1.w)) + (bflo(r2.w) + bflo(r3.w));
        aH3 += (bfhi(r0.w) + bfhi(r1.w)) + (bfhi(r2.w) + bfhi(r3.w));
    }
    for (; i < e; ++i) {
        uint4 r = *(const uint4*)(base + (size_t)ew[i] * 32);
        aL0 += bflo(r.x); aH0 += bfhi(r.x);
        aL1 += bflo(r.y); aH1 += bfhi(r.y);
        aL2 += bflo(r.z); aH2 += bfhi(r.z);
        aL3 += bflo(r.w); aH3 += bfhi(r.w);
    }

    uint4 rs = *(const uint4*)(base + (size_t)v * 32);
    uint4 rx = *(const uint4*)(x0 + (size_t)v * 32 + l * 4);
    float dv = dinv[v];
    float h0 = 0.9f * dv * (aL0 + bflo(rs.x)) + 0.1f * bflo(rx.x);
    float h1 = 0.9f * dv * (aH0 + bfhi(rs.x)) + 0.1f * bfhi(rx.x);
    float h2 = 0.9f * dv * (aL1 + bflo(rs.y)) + 0.1f * bflo(rx.y);
    float h3 = 0.9f * dv * (aH1 + bfhi(rs.y)) + 0.1f * bfhi(rx.y);
    float h4 = 0.9f * dv * (aL2 + bflo(rs.z)) + 0.1f * bflo(rx.z);
    float h5 = 0.9f * dv * (aH2 + bfhi(rs.z)) + 0.1f * bfhi(rx.z);
    float h6 = 0.9f * dv * (aL3 + bflo(rs.w)) + 0.1f * bflo(rx.w);
    float h7 = 0.9f * dv * (aH3 + bfhi(rs.w)) + 0.1f * bfhi(rx.w);

    if (final_step) {
        float* o = hout + (size_t)v * EMBED + l * 8;
        *(float4*)(o)     = make_float4(h0, h1, h2, h3);
        *(float4*)(o + 4) = make_float4(h4, h5, h6, h7);
    } else {
        uint4 g;
        g.x = (u32)f2bf(dv * h0) | ((u32)f2bf(dv * h1) << 16);
        g.y = (u32)f2bf(dv * h2) | ((u32)f2bf(dv * h3) << 16);
        g.z = (u32)f2bf(dv * h4) | ((u32)f2bf(dv * h5) << 16);
        g.w = (u32)f2bf(dv * h6) | ((u32)f2bf(dv * h7) << 16);
        *(uint4*)(gout + (size_t)v * 32 + l * 4) = g;
    }
}

extern "C" void kernel_launch(void* const* d_in, const int* in_sizes, int n_in,
                              void* d_out, int out_size, void* d_ws, size_t ws_size,
                              hipStream_t stream)
{
    const float* x  = (const float*)d_in[0];
    const int*   ei = (const int*)d_in[1];
    const float* W1 = (const float*)d_in[2];
    const float* b1 = (const float*)d_in[3];
    const float* W2 = (const float*)d_in[4];
    const float* b2 = (const float*)d_in[5];
    float* out = (float*)d_out;
    const int* row = ei;
    const int* col = ei + N_EDGES;

    // permanent carve-out (~46 MB)
    char* w = (char*)d_ws;
    u16* x0bf = (u16*)w; w += (size_t)N_NODES * EMBED * 2;   // 12.8 MB
    u16* gA   = (u16*)w; w += (size_t)N_NODES * EMBED * 2;   // 12.8 MB (x0bf+gA = alias region)
    u16* gB   = (u16*)w; w += (size_t)N_NODES * EMBED * 2;   // 12.8 MB
    int* ew   = (int*)w;  w += (size_t)N_EDGES * 4;          // 6.4 MB
    int* off  = (int*)w;  w += ((size_t)(N_NODES + 1) * 4 + 12) & ~15ull;
    int* bucket_base = (int*)w; w += 2048;
    int* bsum = (int*)w; w += 2048;
    float* dinv = (float*)w; w += (size_t)N_NODES * 4;
    u16* W1T = (u16*)w; w += (size_t)IN_DIM * HIDDEN * 2;
    u16* W2T = (u16*)w; w += (size_t)HIDDEN * EMBED * 2;

    // transient binning storage aliased onto x0bf+gA (dead until mlp_mfma runs)
    u32* slot    = (u32*)x0bf;                                     // 19.62 MB
    int* slotcnt = (int*)((char*)x0bf + (size_t)NTILES * NBUCK * CAP * 4);  // +306 KB

    conv_weights<<<(IN_DIM * HIDDEN + HIDDEN * EMBED + 255) / 256, 256, 0, stream>>>(W1, W2, W1T, W2T);
    bin_edges<<<NTILES, 256, 0, stream>>>(row, col, slot, slotcnt, N_EDGES);
    bucket_sums<<<NBUCK, 256, 0, stream>>>(slotcnt, bsum);
    scan_bucket_base<<<1, 64, 0, stream>>>(bsum, bucket_base, off);
    csc_from_bins<<<NBUCK, 1024, 0, stream>>>(slot, slotcnt, bucket_base, off, dinv, ew);

    // MLP after binning (slots alias x0bf/gA); needs dinv (from csc_from_bins)
    mlp_mfma<<<(N_NODES + 31) / 32, 256, 0, stream>>>(x, W1T, b1, W2T, b2, dinv, x0bf, gA, N_NODES);

    // K=10 steps
    const u32* gin = (const u32*)gA;
    for (int s = 0; s < K_STEPS; ++s) {
        int fin = (s == K_STEPS - 1);
        u32* gout = (u32*)((s & 1) ? gA : gB);
        prop8<<<N_NODES / 32, 256, 0, stream>>>(off, ew, gin, (const u32*)x0bf, dinv,
                                                gout, out, fin);
        gin = gout;
    }
}